// Round 6
// baseline (496.059 us; speedup 1.0000x reference)
//
#include <hip/hip_runtime.h>

#define BB 16
#define QQ 900
#define CC 92
#define TT 100
#define INFF 1e18f
#define NK 15   // ceil(QQ / 64)

// ---- DPP wave64 reductions (VALU latency, no DS ops) -------------------
// Butterfly within each 16-lane row (xor1,2,4,8 via quad_perm/half_mirror/
// mirror), then row_bcast15 + row_bcast31 fold rows; lane 63 holds the
// full-wave result. Classic GCN/rocPRIM pattern.
#define DPP_STEP_F(x, ctrl, OP)                                             \
  do {                                                                      \
    float _o = __int_as_float(__builtin_amdgcn_update_dpp(                  \
        __float_as_int(x), __float_as_int(x), (ctrl), 0xF, 0xF, false));    \
    (x) = OP((x), _o);                                                      \
  } while (0)

#define DPP_STEP_I(x, ctrl)                                                 \
  do {                                                                      \
    int _o = __builtin_amdgcn_update_dpp((x), (x), (ctrl), 0xF, 0xF, false);\
    (x) = ((_o) < (x)) ? (_o) : (x);                                        \
  } while (0)

__device__ __forceinline__ float wave_fmin63(float x) {
  DPP_STEP_F(x, 0xB1, fminf);   // quad_perm [1,0,3,2]  (xor 1)
  DPP_STEP_F(x, 0x4E, fminf);   // quad_perm [2,3,0,1]  (xor 2)
  DPP_STEP_F(x, 0x141, fminf);  // row_half_mirror      (xor 4)
  DPP_STEP_F(x, 0x140, fminf);  // row_mirror           (xor 8)
  DPP_STEP_F(x, 0x142, fminf);  // row_bcast15
  DPP_STEP_F(x, 0x143, fminf);  // row_bcast31
  return x;                     // lane 63 valid
}
__device__ __forceinline__ float wave_fmax63(float x) {
  DPP_STEP_F(x, 0xB1, fmaxf);
  DPP_STEP_F(x, 0x4E, fmaxf);
  DPP_STEP_F(x, 0x141, fmaxf);
  DPP_STEP_F(x, 0x140, fmaxf);
  DPP_STEP_F(x, 0x142, fmaxf);
  DPP_STEP_F(x, 0x143, fmaxf);
  return x;
}
__device__ __forceinline__ float wave_fadd63(float x) {
#define ADDF(a, b) ((a) + (b))
  DPP_STEP_F(x, 0xB1, ADDF);
  DPP_STEP_F(x, 0x4E, ADDF);
  DPP_STEP_F(x, 0x141, ADDF);
  DPP_STEP_F(x, 0x140, ADDF);
  DPP_STEP_F(x, 0x142, ADDF);
  DPP_STEP_F(x, 0x143, ADDF);
#undef ADDF
  return x;
}
__device__ __forceinline__ int wave_imin63(int x) {
  DPP_STEP_I(x, 0xB1);
  DPP_STEP_I(x, 0x4E);
  DPP_STEP_I(x, 0x141);
  DPP_STEP_I(x, 0x140);
  DPP_STEP_I(x, 0x142);
  DPP_STEP_I(x, 0x143);
  return x;
}

// ---------------- cost kernel: one WAVE per (b,q) ----------------
__global__ __launch_bounds__(64) void cost_kernel(
    const float* __restrict__ logits,   // [B][Q][C]
    const float* __restrict__ pboxes,   // [B][Q][4]
    const int*   __restrict__ tlabels,  // [B][T]
    const float* __restrict__ tboxes,   // [B][T][4]
    float* __restrict__ cost,           // [B][Q][T]
    float* __restrict__ costT)          // [B][T][Q] or nullptr
{
  const int bq   = blockIdx.x;          // b*QQ + q
  const int b    = bq / QQ;
  const int q    = bq - b * QQ;
  const int lane = threadIdx.x;

  __shared__ float sl[CC];

  // 92 logits over 64 lanes: lane holds [lane] and (lane<28) [64+lane]
  const float a = logits[(size_t)bq * CC + lane];
  const float bb2 = (lane < CC - 64)
                        ? logits[(size_t)bq * CC + 64 + lane]
                        : -3.402823466e38f;

  float mx = fmaxf(a, bb2);
  mx = wave_fmax63(mx);
  const float m = __int_as_float(
      __builtin_amdgcn_readlane(__float_as_int(mx), 63));

  const float e0 = expf(a - m);
  const float e1 = (lane < CC - 64) ? expf(bb2 - m) : 0.0f;
  sl[lane] = e0;
  if (lane < CC - 64) sl[64 + lane] = e1;

  float sm = e0 + e1;
  sm = wave_fadd63(sm);
  const float ssum = __int_as_float(
      __builtin_amdgcn_readlane(__float_as_int(sm), 63));

  const float4 pbv = ((const float4*)pboxes)[bq];
  const float pax1 = pbv.x - 0.5f * pbv.z, pay1 = pbv.y - 0.5f * pbv.w;
  const float pax2 = pbv.x + 0.5f * pbv.z, pay2 = pbv.y + 0.5f * pbv.w;
  const float area_a = (pax2 - pax1) * (pay2 - pay1);

  for (int t = lane; t < TT; t += 64) {
    const int lab = tlabels[b * TT + t];
    const float cc = -(sl[lab] / ssum);

    const float4 tb = ((const float4*)tboxes)[b * TT + t];
    const float cbox = fabsf(pbv.x - tb.x) + fabsf(pbv.y - tb.y) +
                       fabsf(pbv.z - tb.z) + fabsf(pbv.w - tb.w);

    const float bx1 = tb.x - 0.5f * tb.z, by1 = tb.y - 0.5f * tb.w;
    const float bx2 = tb.x + 0.5f * tb.z, by2 = tb.y + 0.5f * tb.w;
    const float area_b = (bx2 - bx1) * (by2 - by1);

    const float ltx = fmaxf(pax1, bx1), lty = fmaxf(pay1, by1);
    const float rbx = fminf(pax2, bx2), rby = fminf(pay2, by2);
    const float iw = fmaxf(rbx - ltx, 0.0f), ih = fmaxf(rby - lty, 0.0f);
    const float inter = iw * ih;
    const float uni = area_a + area_b - inter;
    const float iou = inter / uni;

    const float cx1 = fminf(pax1, bx1), cy1 = fminf(pay1, by1);
    const float cx2 = fmaxf(pax2, bx2), cy2 = fmaxf(pay2, by2);
    const float cw = fmaxf(cx2 - cx1, 0.0f), ch = fmaxf(cy2 - cy1, 0.0f);
    const float ac = cw * ch;
    const float giou = iou - (ac - uni) / ac;

    const float cval = 5.0f * cbox + cc - 2.0f * giou;
    cost[(size_t)bq * TT + t] = cval;
    if (costT) costT[((size_t)b * TT + t) * QQ + q] = cval;
  }
}

// ---------------- hungarian kernel: ONE WAVE per batch, barrier-free ----
// Column j owned by lane (j&63), slot (j>>6). v/minv/cost-row/used-mask in
// registers; way in LDS (fire-and-forget ds_write, read only at augment);
// u in 2 regs/lane + tree bitmask; u[i0] via v_readlane (uniform lane).
// Argmin: DPP value-reduce then DPP index-reduce over exact-equality
// candidates -> global lowest-index tie-break == jnp.argmin.
// amdgpu_waves_per_eu(1): direct backend attribute to lift the 64-VGPR
// occupancy cap (launch_bounds 2nd arg was ignored, r4==r5 binaries).
__global__ void __launch_bounds__(64)
__attribute__((amdgpu_waves_per_eu(1)))
hungarian_kernel(
    const float* __restrict__ cost,    // [B][Q][T]
    const float* __restrict__ costT,   // [B][T][Q] or nullptr
    float* __restrict__ out_q,         // [B][T]
    float* __restrict__ out_t)         // [B][T]
{
  const int b    = blockIdx.x;
  const int lane = threadIdx.x;

  __shared__ int p_lds[QQ + 1];
  __shared__ int way_lds[QQ];
  __shared__ int qpt[TT];

  // generic addressing: cost value(i0, j) = base[i0*rs + j*cs]
  const float* base;
  size_t rs, cs;
  if (costT) { base = costT + (size_t)b * TT * QQ; rs = QQ; cs = 1; }
  else       { base = cost  + (size_t)b * QQ * TT; rs = 1;  cs = TT; }

  for (int j = lane; j <= QQ; j += 64) p_lds[j] = TT;

  float u0 = 0.0f, u1 = 0.0f;   // u[lane], u[64+lane]
  float v[NK];
#pragma unroll
  for (int k = 0; k < NK; ++k) v[k] = 0.0f;

  // prefetch row 0
  float c[NK];
#pragma unroll
  for (int k = 0; k < NK; ++k) {
    const int j = k * 64 + lane;
    c[k] = (j < QQ) ? base[(size_t)j * cs] : 0.0f;
  }

  for (int i = 0; i < TT; ++i) {
    p_lds[QQ] = i;               // all lanes, same addr, same value

    float minv[NK];
#pragma unroll
    for (int k = 0; k < NK; ++k) minv[k] = INFF;
    unsigned umask = 0;          // used columns (my lane's 15 slots)
    bool t0 = false, t1 = false; // rows in tree: lane, 64+lane

    int i0 = i;
    int j0 = QQ;
    int jfin;

    // u[i0] for the row start (readlane: uniform lane index, VALU-cheap)
    float us = (i0 < 64) ? u0 : u1;
    float ui0 = __int_as_float(
        __builtin_amdgcn_readlane(__float_as_int(us), i0 & 63));

    while (true) {
      // add row i0 to the tree; mark column j0 used (real cols only)
      t0 = t0 || (i0 == lane);
      t1 = t1 || (i0 == 64 + lane);
      if (j0 != QQ) {
        if ((j0 & 63) == lane) umask |= (1u << (j0 >> 6));
      }

      // scan: update minv/way over unused columns, track local argmin
      float lmin = INFF;
      int   lidx = QQ;
#pragma unroll
      for (int k = 0; k < NK; ++k) {
        const int j = k * 64 + lane;
        if (j < QQ && !((umask >> k) & 1u)) {
          const float cur = c[k] - ui0 - v[k];
          if (cur < minv[k]) { minv[k] = cur; way_lds[j] = j0; }
          if (minv[k] < lmin) { lmin = minv[k]; lidx = j; }
        }
      }

      // DPP argmin: value reduce, then lowest index among exact minima
      float red = wave_fmin63(lmin);
      const float delta = __int_as_float(
          __builtin_amdgcn_readlane(__float_as_int(red), 63));
      int cand = (lmin == delta) ? lidx : 0x7FFFFFFF;
      int redi = wave_imin63(cand);
      const int j1 = __builtin_amdgcn_readlane(redi, 63);

      // row matched to j1 (broadcast LDS read; only DS read in the loop)
      int i0n = p_lds[j1];
      i0n = __builtin_amdgcn_readfirstlane(i0n);  // canonicalize uniform
      const bool fin = (i0n == TT);

      // potential updates (independent of i0n -> overlap the p-read wait)
      u0 += t0 ? delta : 0.0f;
      u1 += t1 ? delta : 0.0f;
#pragma unroll
      for (int k = 0; k < NK; ++k) {
        const bool uk = (umask >> k) & 1u;
        v[k]    -= uk ? delta : 0.0f;
        minv[k] -= uk ? 0.0f  : delta;
      }

      if (!fin) {
        // u[i0n] via readlane (uniform); selected lane's component is
        // not in the tree, so pre/post update order is equivalent
        float us2 = (i0n < 64) ? u0 : u1;
        ui0 = __int_as_float(
            __builtin_amdgcn_readlane(__float_as_int(us2), i0n & 63));
        // prefetch next scan row; latency overlaps loop-back + scan front
#pragma unroll
        for (int k = 0; k < NK; ++k) {
          const int j = k * 64 + lane;
          if (j < QQ) c[k] = base[(size_t)i0n * rs + (size_t)j * cs];
        }
      }
      asm volatile("" ::: "memory");  // compiler fence: pin load placement

      if (fin) { jfin = j1; break; }
      j0 = j1;
      i0 = i0n;
    }

    // prefetch row i+1 (next Dijkstra start) under the augment walk
    if (i + 1 < TT) {
#pragma unroll
      for (int k = 0; k < NK; ++k) {
        const int jj = k * 64 + lane;
        if (jj < QQ) c[k] = base[(size_t)(i + 1) * rs + (size_t)jj * cs];
      }
    }

    // augment along the way chain (uniform serial walk)
    int j = jfin;
    while (j != QQ) {
      const int jn = way_lds[j];
      const int pj = p_lds[jn];  // jn may be QQ -> p_lds[QQ] == i
      p_lds[j] = pj;             // all lanes same addr, same value
      j = jn;
    }
    asm volatile("" ::: "memory");
  }

  // q_per_t: query assigned to each target row
#pragma unroll
  for (int k = 0; k < NK; ++k) {
    const int j = k * 64 + lane;
    if (j < QQ) {
      const int r = p_lds[j];
      if (r < TT) qpt[r] = j;
    }
  }
  __syncthreads();  // once per kernel; cheap insurance before rank pass

  // argsort(q_per_t) via rank counting (values are distinct)
  for (int t = lane; t < TT; t += 64) {
    const int myq = qpt[t];
    int rank = 0;
    for (int t2 = 0; t2 < TT; ++t2) rank += (qpt[t2] < myq) ? 1 : 0;
    out_q[b * TT + rank] = (float)myq;
    out_t[b * TT + rank] = (float)t;
  }
}

extern "C" void kernel_launch(void* const* d_in, const int* in_sizes, int n_in,
                              void* d_out, int out_size, void* d_ws, size_t ws_size,
                              hipStream_t stream) {
  const float* logits  = (const float*)d_in[0];
  const float* pboxes  = (const float*)d_in[1];
  const int*   tlabels = (const int*)d_in[2];
  const float* tboxes  = (const float*)d_in[3];

  float* out  = (float*)d_out;
  float* cost = out;                               // [B][Q][T]
  float* oq   = out + (size_t)BB * QQ * TT;        // [B][T]
  float* ot   = oq + (size_t)BB * TT;              // [B][T]

  const size_t costT_bytes = (size_t)BB * TT * QQ * sizeof(float);
  float* costT = (ws_size >= costT_bytes) ? (float*)d_ws : nullptr;

  hipLaunchKernelGGL(cost_kernel, dim3(BB * QQ), dim3(64), 0, stream,
                     logits, pboxes, tlabels, tboxes, cost, costT);
  hipLaunchKernelGGL(hungarian_kernel, dim3(BB), dim3(64), 0, stream,
                     cost, costT, oq, ot);
}

// Round 7
// 190.731 us; speedup vs baseline: 2.6008x; 2.6008x over previous
//
#include <hip/hip_runtime.h>

#define BB 16
#define QQ 900
#define QP 960           // padded column count = 15*64 (pad cols hold +INF)
#define VIRT QP          // virtual start column index
#define CC 92
#define TT 100
#define INFF 1e18f
#define NK 15            // QP / 64

// ---- DPP wave64 reductions (VALU latency, no DS ops) -------------------
#define DPP_STEP_F(x, ctrl, OP)                                             \
  do {                                                                      \
    float _o = __int_as_float(__builtin_amdgcn_update_dpp(                  \
        __float_as_int(x), __float_as_int(x), (ctrl), 0xF, 0xF, false));    \
    (x) = OP((x), _o);                                                      \
  } while (0)

#define DPP_STEP_I(x, ctrl)                                                 \
  do {                                                                      \
    int _o = __builtin_amdgcn_update_dpp((x), (x), (ctrl), 0xF, 0xF, false);\
    (x) = ((_o) < (x)) ? (_o) : (x);                                        \
  } while (0)

__device__ __forceinline__ float wave_fmin63(float x) {
  DPP_STEP_F(x, 0xB1, fminf);   // xor 1
  DPP_STEP_F(x, 0x4E, fminf);   // xor 2
  DPP_STEP_F(x, 0x141, fminf);  // xor 4
  DPP_STEP_F(x, 0x140, fminf);  // xor 8
  DPP_STEP_F(x, 0x142, fminf);  // row_bcast15
  DPP_STEP_F(x, 0x143, fminf);  // row_bcast31
  return x;                     // lane 63 valid
}
__device__ __forceinline__ float wave_fmax63(float x) {
  DPP_STEP_F(x, 0xB1, fmaxf);
  DPP_STEP_F(x, 0x4E, fmaxf);
  DPP_STEP_F(x, 0x141, fmaxf);
  DPP_STEP_F(x, 0x140, fmaxf);
  DPP_STEP_F(x, 0x142, fmaxf);
  DPP_STEP_F(x, 0x143, fmaxf);
  return x;
}
__device__ __forceinline__ float wave_fadd63(float x) {
#define ADDF(a, b) ((a) + (b))
  DPP_STEP_F(x, 0xB1, ADDF);
  DPP_STEP_F(x, 0x4E, ADDF);
  DPP_STEP_F(x, 0x141, ADDF);
  DPP_STEP_F(x, 0x140, ADDF);
  DPP_STEP_F(x, 0x142, ADDF);
  DPP_STEP_F(x, 0x143, ADDF);
#undef ADDF
  return x;
}
__device__ __forceinline__ int wave_imin63(int x) {
  DPP_STEP_I(x, 0xB1);
  DPP_STEP_I(x, 0x4E);
  DPP_STEP_I(x, 0x141);
  DPP_STEP_I(x, 0x140);
  DPP_STEP_I(x, 0x142);
  DPP_STEP_I(x, 0x143);
  return x;
}

// ---------------- cost kernel: one WAVE per (b,q) ----------------
// ctp = costT column stride (QP padded, QQ unpadded, 0 = no costT)
__global__ __launch_bounds__(64) void cost_kernel(
    const float* __restrict__ logits,   // [B][Q][C]
    const float* __restrict__ pboxes,   // [B][Q][4]
    const int*   __restrict__ tlabels,  // [B][T]
    const float* __restrict__ tboxes,   // [B][T][4]
    float* __restrict__ cost,           // [B][Q][T]
    float* __restrict__ costT,          // [B][T][ctp] or nullptr
    int ctp)
{
  const int bq   = blockIdx.x;          // b*QQ + q
  const int b    = bq / QQ;
  const int q    = bq - b * QQ;
  const int lane = threadIdx.x;

  __shared__ float sl[CC];

  const float a = logits[(size_t)bq * CC + lane];
  const float bb2 = (lane < CC - 64)
                        ? logits[(size_t)bq * CC + 64 + lane]
                        : -3.402823466e38f;

  float mx = fmaxf(a, bb2);
  mx = wave_fmax63(mx);
  const float m = __int_as_float(
      __builtin_amdgcn_readlane(__float_as_int(mx), 63));

  const float e0 = expf(a - m);
  const float e1 = (lane < CC - 64) ? expf(bb2 - m) : 0.0f;
  sl[lane] = e0;
  if (lane < CC - 64) sl[64 + lane] = e1;

  float sm = e0 + e1;
  sm = wave_fadd63(sm);
  const float ssum = __int_as_float(
      __builtin_amdgcn_readlane(__float_as_int(sm), 63));

  const float4 pbv = ((const float4*)pboxes)[bq];
  const float pax1 = pbv.x - 0.5f * pbv.z, pay1 = pbv.y - 0.5f * pbv.w;
  const float pax2 = pbv.x + 0.5f * pbv.z, pay2 = pbv.y + 0.5f * pbv.w;
  const float area_a = (pax2 - pax1) * (pay2 - pay1);

  for (int t = lane; t < TT; t += 64) {
    const int lab = tlabels[b * TT + t];
    const float cc = -(sl[lab] / ssum);

    const float4 tb = ((const float4*)tboxes)[b * TT + t];
    const float cbox = fabsf(pbv.x - tb.x) + fabsf(pbv.y - tb.y) +
                       fabsf(pbv.z - tb.z) + fabsf(pbv.w - tb.w);

    const float bx1 = tb.x - 0.5f * tb.z, by1 = tb.y - 0.5f * tb.w;
    const float bx2 = tb.x + 0.5f * tb.z, by2 = tb.y + 0.5f * tb.w;
    const float area_b = (bx2 - bx1) * (by2 - by1);

    const float ltx = fmaxf(pax1, bx1), lty = fmaxf(pay1, by1);
    const float rbx = fminf(pax2, bx2), rby = fminf(pay2, by2);
    const float iw = fmaxf(rbx - ltx, 0.0f), ih = fmaxf(rby - lty, 0.0f);
    const float inter = iw * ih;
    const float uni = area_a + area_b - inter;
    const float iou = inter / uni;

    const float cx1 = fminf(pax1, bx1), cy1 = fminf(pay1, by1);
    const float cx2 = fmaxf(pax2, bx2), cy2 = fmaxf(pay2, by2);
    const float cw = fmaxf(cx2 - cx1, 0.0f), ch = fmaxf(cy2 - cy1, 0.0f);
    const float ac = cw * ch;
    const float giou = iou - (ac - uni) / ac;

    const float cval = 5.0f * cbox + cc - 2.0f * giou;
    cost[(size_t)bq * TT + t] = cval;
    if (ctp) costT[((size_t)b * TT + t) * ctp + q] = cval;
  }
  // fill pad columns with +INF (never win the argmin)
  if (ctp == QP && q < QP - QQ) {
    for (int t = lane; t < TT; t += 64)
      costT[((size_t)b * TT + t) * QP + QQ + q] = INFF;
  }
}

// ------- specialized hungarian: padded costT, ONE WAVE per batch --------
// Column j in [0,QP) owned by lane (j&63), slot (j>>6); pads hold +INF.
// Register state: c[15]+minv[15]+v[15]=45 VGPR + ~12 temps -> fits the
// 64-VGPR cap with ZERO spill (the r4-r6 regression). Row base address is
// scalar (SGPR mul); the 15 loads/way-writes share one lane*4 VGPR with
// k*256 immediate offsets. way/p in LDS, u in 2 regs + readlane.
__global__ void __launch_bounds__(64, 1)
__attribute__((amdgpu_waves_per_eu(1)))
hungarianT_kernel(
    const float* __restrict__ ct,      // [B][T][QP] padded transposed cost
    float* __restrict__ out_q,         // [B][T]
    float* __restrict__ out_t)         // [B][T]
{
  const int b    = blockIdx.x;
  const int lane = threadIdx.x;

  __shared__ int p_lds[QP + 1];
  __shared__ int way_lds[QP];
  __shared__ int qpt[TT];

  const float* __restrict__ base = ct + (size_t)b * TT * QP;

  for (int j = lane; j <= QP; j += 64) p_lds[j] = TT;

  float u0 = 0.0f, u1 = 0.0f;   // u[lane], u[64+lane]
  float v[NK];
#pragma unroll
  for (int k = 0; k < NK; ++k) v[k] = 0.0f;

  // prefetch row 0
  float c[NK];
#pragma unroll
  for (int k = 0; k < NK; ++k) c[k] = base[k * 64 + lane];

  for (int i = 0; i < TT; ++i) {
    p_lds[VIRT] = i;             // all lanes, same addr, same value

    float minv[NK];
#pragma unroll
    for (int k = 0; k < NK; ++k) minv[k] = INFF;
    unsigned umask = 0;          // used columns (my lane's 15 slots)
    bool t0 = false, t1 = false; // rows in tree: lane, 64+lane

    int i0 = i;
    int j0 = VIRT;
    int jfin;

    float us = (i0 < 64) ? u0 : u1;
    float ui0 = __int_as_float(
        __builtin_amdgcn_readlane(__float_as_int(us), i0 & 63));

    while (true) {
      // add row i0 to tree; mark column j0 used (real cols only)
      t0 = t0 || (i0 == lane);
      t1 = t1 || (i0 == 64 + lane);
      if (j0 != VIRT && (j0 & 63) == lane) umask |= (1u << (j0 >> 6));

      // scan: minv/way update + per-lane argmin as 4-bit slot index
      float lmin  = INFF;
      int   kbest = 0;
#pragma unroll
      for (int k = 0; k < NK; ++k) {
        const bool  uk  = (umask >> k) & 1u;
        const float cur = c[k] - ui0 - v[k];
        const bool  imp = !uk && (cur < minv[k]);
        if (imp) { minv[k] = cur; way_lds[k * 64 + lane] = j0; }
        const float eff = uk ? INFF : minv[k];
        if (eff < lmin) { lmin = eff; kbest = k; }
      }
      const int lidx = kbest * 64 + lane;

      // DPP argmin: value reduce, then lowest index among exact minima
      float red = wave_fmin63(lmin);
      const float delta = __int_as_float(
          __builtin_amdgcn_readlane(__float_as_int(red), 63));
      int cand = (lmin == delta) ? lidx : 0x7FFFFFFF;
      int redi = wave_imin63(cand);
      const int j1 = __builtin_amdgcn_readlane(redi, 63);

      // row matched to j1 (broadcast LDS read; only DS read in the loop)
      int i0n = p_lds[j1];
      i0n = __builtin_amdgcn_readfirstlane(i0n);
      const bool fin = (i0n == TT);

      // prefetch next scan row ASAP (scalar row base, imm offsets)
      if (!fin) {
        const float* __restrict__ row = base + (size_t)i0n * QP;
#pragma unroll
        for (int k = 0; k < NK; ++k) c[k] = row[k * 64 + lane];
      }

      // potential updates: pure register ops, overlap the load latency
      u0 += t0 ? delta : 0.0f;
      u1 += t1 ? delta : 0.0f;
#pragma unroll
      for (int k = 0; k < NK; ++k) {
        const bool uk = (umask >> k) & 1u;
        v[k]    -= uk ? delta : 0.0f;
        minv[k] -= uk ? 0.0f  : delta;
      }

      if (fin) { jfin = j1; break; }
      // u[i0n] for next scan (i0n not yet in tree -> unaffected by update)
      float us2 = (i0n < 64) ? u0 : u1;
      ui0 = __int_as_float(
          __builtin_amdgcn_readlane(__float_as_int(us2), i0n & 63));
      j0 = j1;
      i0 = i0n;
    }

    // prefetch row i+1 (next Dijkstra start) under the augment walk
    if (i + 1 < TT) {
      const float* __restrict__ row = base + (size_t)(i + 1) * QP;
#pragma unroll
      for (int k = 0; k < NK; ++k) c[k] = row[k * 64 + lane];
    }

    // augment along the way chain (uniform serial walk)
    int j = jfin;
    while (j != VIRT) {
      const int jn = way_lds[j];
      const int pj = p_lds[jn];  // jn may be VIRT -> p_lds[VIRT] == i
      p_lds[j] = pj;             // all lanes same addr, same value
      j = jn;
    }
    asm volatile("" ::: "memory");
  }

  // q_per_t: query assigned to each target row (pads have p == TT)
#pragma unroll
  for (int k = 0; k < NK; ++k) {
    const int j = k * 64 + lane;
    const int r = p_lds[j];
    if (r < TT) qpt[r] = j;
  }
  __syncthreads();

  // argsort(q_per_t) via rank counting (values are distinct)
  for (int t = lane; t < TT; t += 64) {
    const int myq = qpt[t];
    int rank = 0;
    for (int t2 = 0; t2 < TT; ++t2) rank += (qpt[t2] < myq) ? 1 : 0;
    out_q[b * TT + rank] = (float)myq;
    out_t[b * TT + rank] = (float)t;
  }
}

// ---------------- generic fallback (r6 kernel, verified) ----------------
__global__ void __launch_bounds__(64)
hungarian_kernel(
    const float* __restrict__ cost,    // [B][Q][T]
    const float* __restrict__ costT,   // [B][T][QQ] or nullptr
    float* __restrict__ out_q,
    float* __restrict__ out_t)
{
  const int b    = blockIdx.x;
  const int lane = threadIdx.x;

  __shared__ int p_lds[QQ + 1];
  __shared__ int way_lds[QQ];
  __shared__ int qpt[TT];

  const float* base;
  size_t rs, cs;
  if (costT) { base = costT + (size_t)b * TT * QQ; rs = QQ; cs = 1; }
  else       { base = cost  + (size_t)b * QQ * TT; rs = 1;  cs = TT; }

  for (int j = lane; j <= QQ; j += 64) p_lds[j] = TT;

  float u0 = 0.0f, u1 = 0.0f;
  float v[NK];
#pragma unroll
  for (int k = 0; k < NK; ++k) v[k] = 0.0f;

  float c[NK];
#pragma unroll
  for (int k = 0; k < NK; ++k) {
    const int j = k * 64 + lane;
    c[k] = (j < QQ) ? base[(size_t)j * cs] : 0.0f;
  }

  for (int i = 0; i < TT; ++i) {
    p_lds[QQ] = i;

    float minv[NK];
#pragma unroll
    for (int k = 0; k < NK; ++k) minv[k] = INFF;
    unsigned umask = 0;
    bool t0 = false, t1 = false;

    int i0 = i;
    int j0 = QQ;
    int jfin;

    float us = (i0 < 64) ? u0 : u1;
    float ui0 = __int_as_float(
        __builtin_amdgcn_readlane(__float_as_int(us), i0 & 63));

    while (true) {
      t0 = t0 || (i0 == lane);
      t1 = t1 || (i0 == 64 + lane);
      if (j0 != QQ) {
        if ((j0 & 63) == lane) umask |= (1u << (j0 >> 6));
      }

      float lmin = INFF;
      int   lidx = QQ;
#pragma unroll
      for (int k = 0; k < NK; ++k) {
        const int j = k * 64 + lane;
        if (j < QQ && !((umask >> k) & 1u)) {
          const float cur = c[k] - ui0 - v[k];
          if (cur < minv[k]) { minv[k] = cur; way_lds[j] = j0; }
          if (minv[k] < lmin) { lmin = minv[k]; lidx = j; }
        }
      }

      float red = wave_fmin63(lmin);
      const float delta = __int_as_float(
          __builtin_amdgcn_readlane(__float_as_int(red), 63));
      int cand = (lmin == delta) ? lidx : 0x7FFFFFFF;
      int redi = wave_imin63(cand);
      const int j1 = __builtin_amdgcn_readlane(redi, 63);

      int i0n = p_lds[j1];
      i0n = __builtin_amdgcn_readfirstlane(i0n);
      const bool fin = (i0n == TT);

      u0 += t0 ? delta : 0.0f;
      u1 += t1 ? delta : 0.0f;
#pragma unroll
      for (int k = 0; k < NK; ++k) {
        const bool uk = (umask >> k) & 1u;
        v[k]    -= uk ? delta : 0.0f;
        minv[k] -= uk ? 0.0f  : delta;
      }

      if (!fin) {
        float us2 = (i0n < 64) ? u0 : u1;
        ui0 = __int_as_float(
            __builtin_amdgcn_readlane(__float_as_int(us2), i0n & 63));
#pragma unroll
        for (int k = 0; k < NK; ++k) {
          const int j = k * 64 + lane;
          if (j < QQ) c[k] = base[(size_t)i0n * rs + (size_t)j * cs];
        }
      }
      asm volatile("" ::: "memory");

      if (fin) { jfin = j1; break; }
      j0 = j1;
      i0 = i0n;
    }

    if (i + 1 < TT) {
#pragma unroll
      for (int k = 0; k < NK; ++k) {
        const int jj = k * 64 + lane;
        if (jj < QQ) c[k] = base[(size_t)(i + 1) * rs + (size_t)jj * cs];
      }
    }

    int j = jfin;
    while (j != QQ) {
      const int jn = way_lds[j];
      const int pj = p_lds[jn];
      p_lds[j] = pj;
      j = jn;
    }
    asm volatile("" ::: "memory");
  }

#pragma unroll
  for (int k = 0; k < NK; ++k) {
    const int j = k * 64 + lane;
    if (j < QQ) {
      const int r = p_lds[j];
      if (r < TT) qpt[r] = j;
    }
  }
  __syncthreads();

  for (int t = lane; t < TT; t += 64) {
    const int myq = qpt[t];
    int rank = 0;
    for (int t2 = 0; t2 < TT; ++t2) rank += (qpt[t2] < myq) ? 1 : 0;
    out_q[b * TT + rank] = (float)myq;
    out_t[b * TT + rank] = (float)t;
  }
}

extern "C" void kernel_launch(void* const* d_in, const int* in_sizes, int n_in,
                              void* d_out, int out_size, void* d_ws, size_t ws_size,
                              hipStream_t stream) {
  const float* logits  = (const float*)d_in[0];
  const float* pboxes  = (const float*)d_in[1];
  const int*   tlabels = (const int*)d_in[2];
  const float* tboxes  = (const float*)d_in[3];

  float* out  = (float*)d_out;
  float* cost = out;                               // [B][Q][T]
  float* oq   = out + (size_t)BB * QQ * TT;        // [B][T]
  float* ot   = oq + (size_t)BB * TT;              // [B][T]

  const size_t padded_bytes = (size_t)BB * TT * QP * sizeof(float);
  const size_t plain_bytes  = (size_t)BB * TT * QQ * sizeof(float);

  if (ws_size >= padded_bytes) {
    float* costT = (float*)d_ws;
    hipLaunchKernelGGL(cost_kernel, dim3(BB * QQ), dim3(64), 0, stream,
                       logits, pboxes, tlabels, tboxes, cost, costT, QP);
    hipLaunchKernelGGL(hungarianT_kernel, dim3(BB), dim3(64), 0, stream,
                       costT, oq, ot);
  } else if (ws_size >= plain_bytes) {
    float* costT = (float*)d_ws;
    hipLaunchKernelGGL(cost_kernel, dim3(BB * QQ), dim3(64), 0, stream,
                       logits, pboxes, tlabels, tboxes, cost, costT, QQ);
    hipLaunchKernelGGL(hungarian_kernel, dim3(BB), dim3(64), 0, stream,
                       cost, costT, oq, ot);
  } else {
    hipLaunchKernelGGL(cost_kernel, dim3(BB * QQ), dim3(64), 0, stream,
                       logits, pboxes, tlabels, tboxes, cost, (float*)nullptr, 0);
    hipLaunchKernelGGL(hungarian_kernel, dim3(BB), dim3(64), 0, stream,
                       cost, (const float*)nullptr, oq, ot);
  }
}